// Round 8
// baseline (60.609 us; speedup 1.0000x reference)
//
#include <hip/hip_runtime.h>

typedef unsigned short u16;
typedef __attribute__((ext_vector_type(4))) float f32x4;
typedef __attribute__((ext_vector_type(8))) short bf16x8;
typedef __attribute__((ext_vector_type(4))) u16 u16x4;

#define MFMA(a, b, c) __builtin_amdgcn_mfma_f32_16x16x32_bf16(a, b, c, 0, 0, 0)

__device__ __forceinline__ u16 f2bf(float f) {
    unsigned u = __float_as_uint(f);
    u += 0x7fffu + ((u >> 16) & 1u);   // round-to-nearest-even
    return (u16)(u >> 16);
}
__device__ __forceinline__ float bf2f(u16 h) {
    unsigned u = ((unsigned)h) << 16;
    return __uint_as_float(u);
}

__device__ __forceinline__ void load_lds16(const void* g, void* l) {
    __builtin_amdgcn_global_load_lds((const __attribute__((address_space(1))) void*)g,
                                     (__attribute__((address_space(3))) void*)l,
                                     16, 0, 0);
}

// ---------------------------------------------------------------------------
// Kernel 1: pack Wq|Wk|Wv (fp32 [1024][64]) -> Wtt bf16, tile-major + swizzled.
// ---------------------------------------------------------------------------
__global__ void wt_pack(const float* __restrict__ Wq, const float* __restrict__ Wk,
                        const float* __restrict__ Wv, u16* __restrict__ Wtt) {
    const int k = blockIdx.x;        // 0..1023
    const int n = threadIdx.x;       // 0..191
    const float* W = (n < 64) ? Wq : (n < 128 ? Wk : Wv);
    const float v = W[(size_t)k * 64 + (n & 63)];
    const int kt = k >> 6, ks = k & 63, c = ks >> 3, ci = ks & 7;
    Wtt[(size_t)kt * 12288 + n * 64 + (((c ^ (n & 7)) << 3) + ci)] = f2bf(v);
}

// ---------------------------------------------------------------------------
// Kernel 2: qkv projection, m97-structure, BM=64 / 8 waves / 256 blocks
// (halves the Wt L2->LDS re-stream vs BM=32: 192MB -> 96MB).
// Waves 2M x 4N: wave owns 32 rows x 48 cols. LDS 80KB dbuf.
// Q output pre-scaled by log2(e)/sqrt(1024).
// ---------------------------------------------------------------------------
__global__ __launch_bounds__(512, 2) void qkv_gemm(const float* __restrict__ x,
                                                   const u16* __restrict__ Wtt,
                                                   u16* __restrict__ qo,
                                                   u16* __restrict__ ko,
                                                   u16* __restrict__ vT) {
    const int tid = threadIdx.x;
    const int lane = tid & 63, wave = tid >> 6;
    const int lr = lane & 15, lg = lane >> 4;
    const int wr = wave >> 2, wc = wave & 3;
    const int m0 = blockIdx.x * 64;

    __shared__ __align__(16) float xs[2][64 * 64];   // 16KB each
    __shared__ __align__(16) u16 ws[2][192 * 64];    // 24KB each

    f32x4 acc[2][3];
#pragma unroll
    for (int m = 0; m < 2; ++m)
#pragma unroll
        for (int n = 0; n < 3; ++n) acc[m][n] = (f32x4){0.f, 0.f, 0.f, 0.f};

#define QSTAGE(bufi, kt_)                                                              \
    {                                                                                  \
        _Pragma("unroll") for (int j = 0; j < 2; ++j) {                                \
            const int cid = j * 512 + tid;                                             \
            const int row = cid >> 4, cc = cid & 15;                                   \
            load_lds16(x + (size_t)(m0 + row) * 1024 + (kt_)*64 +                      \
                           ((cc ^ (row & 7)) << 2),                                    \
                       &xs[bufi][(j * 512 + wave * 64) * 4]);                          \
        }                                                                              \
        _Pragma("unroll") for (int j = 0; j < 3; ++j) {                                \
            const int cid = j * 512 + tid;                                             \
            load_lds16(Wtt + (size_t)(kt_)*12288 + cid * 8,                            \
                       &ws[bufi][(j * 512 + wave * 64) * 8]);                          \
        }                                                                              \
    }

    QSTAGE(0, 0);
    __syncthreads();

    for (int kt = 0; kt < 16; ++kt) {
        const int cur = kt & 1;
        if (kt < 15) QSTAGE(cur ^ 1, kt + 1);
#pragma unroll
        for (int h = 0; h < 2; ++h) {
            bf16x8 a[2];
#pragma unroll
            for (int mm = 0; mm < 2; ++mm) {
                const int rr = wr * 32 + mm * 16 + lr;
                const int c0 = h * 8 + lg * 2;
                f32x4 f0 = *(const f32x4*)&xs[cur][rr * 64 + ((c0 ^ (rr & 7)) << 2)];
                f32x4 f1 = *(const f32x4*)&xs[cur][rr * 64 + (((c0 + 1) ^ (rr & 7)) << 2)];
                bf16x8 t;
#pragma unroll
                for (int i = 0; i < 4; ++i) {
                    t[i] = (short)f2bf(f0[i]);
                    t[i + 4] = (short)f2bf(f1[i]);
                }
                a[mm] = t;
            }
#pragma unroll
            for (int nl = 0; nl < 3; ++nl) {
                const int row = wc * 48 + nl * 16 + lr;
                const int cb = h * 4 + lg;
                const bf16x8 b = *(const bf16x8*)&ws[cur][row * 64 + ((cb ^ (row & 7)) << 3)];
                acc[0][nl] = MFMA(a[0], b, acc[0][nl]);
                acc[1][nl] = MFMA(a[1], b, acc[1][nl]);
            }
        }
        __syncthreads();
    }

    const float SCQ = 0.0450842200277801f;   // log2(e)/sqrt(1024)
    const int bb = m0 >> 11;
    const int tb = m0 & 2047;
#pragma unroll
    for (int mm = 0; mm < 2; ++mm)
#pragma unroll
        for (int nl = 0; nl < 3; ++nl) {
            const int col = wc * 48 + nl * 16 + lr;
            const int rl = wr * 32 + mm * 16 + lg * 4;
            if (col < 64) {
#pragma unroll
                for (int r = 0; r < 4; ++r)
                    qo[(size_t)(m0 + rl + r) * 64 + col] = f2bf(acc[mm][nl][r] * SCQ);
            } else if (col < 128) {
#pragma unroll
                for (int r = 0; r < 4; ++r)
                    ko[(size_t)(m0 + rl + r) * 64 + (col - 64)] = f2bf(acc[mm][nl][r]);
            } else {
                u16x4 pk;
#pragma unroll
                for (int r = 0; r < 4; ++r) pk[r] = f2bf(acc[mm][nl][r]);
                *(u16x4*)&vT[(size_t)(bb * 64 + (col - 128)) * 2048 + tb + rl] = pk;
            }
        }
}

// ---------------------------------------------------------------------------
// Kernel 3: causal attention, 2-phase global_load_lds, BK=128 (two 64-tiles
// per stage/barrier pair -> half the vmcnt(0) drains). LDS 73KB, 2 blocks/CU.
// Swapped QK^T (S^T), fixed-max softmax, bf16 partials.
// ---------------------------------------------------------------------------
#define PPITCH 72
__global__ __launch_bounds__(256, 2) void attn_part(const u16* __restrict__ q,
                                                    const u16* __restrict__ k,
                                                    const u16* __restrict__ vT,
                                                    u16* __restrict__ Opb,
                                                    float* __restrict__ Lp) {
    const int b = blockIdx.x & 7;
    int g = blockIdx.x >> 3;                  // 0..79, heavy-first
    int qt = 31, rem = g;
    while (rem >= (qt >> 3) + 1) { rem -= (qt >> 3) + 1; --qt; }
    const int c0 = rem;
    const int q0 = qt * 64;
    const int kv_lo = c0 * 512;
    const int kv_hi = min(kv_lo + 512, q0 + 64);
    const int niter = (kv_hi - kv_lo + 127) >> 7;
    const int slot = (b * 32 + qt) * 4 + c0;

    __shared__ __align__(16) u16 lK[2][128 * 64];    // 16KB each, rows=kv
    __shared__ __align__(16) u16 lV[2][64 * 128];    // 16KB each, rows=h
    __shared__ __align__(16) u16 lP[4][16 * PPITCH]; // per-wave P

    const int tid = threadIdx.x;
    const int wave = tid >> 6, lane = tid & 63;
    const int lr = lane & 15, lg = lane >> 4;

    const u16* qb = q + (size_t)b * 2048 * 64;
    const u16* kb = k + (size_t)b * 2048 * 64;
    const u16* vb = vT + (size_t)b * 64 * 2048;

    const int myrow = q0 + wave * 16 + lr;
    const bf16x8 qf0 = *(const bf16x8*)(qb + (size_t)myrow * 64 + lg * 8);
    const bf16x8 qf1 = *(const bf16x8*)(qb + (size_t)myrow * 64 + 32 + lg * 8);

    f32x4 oacc[4];
#pragma unroll
    for (int n = 0; n < 4; ++n) oacc[n] = (f32x4){0.f, 0.f, 0.f, 0.f};
    float rs = 0.f;

    // K: [128][64] rows=kv, 8 chunks/row, swizzle low3 of chunk with row&7.
    // V: [64][128] rows=h, 16 chunks/row, swizzle low3 (bit3 = kv-half kept).
#define ASTAGE(bufi, kv0_)                                                             \
    {                                                                                  \
        _Pragma("unroll") for (int j = 0; j < 4; ++j) {                                \
            const int cid = j * 256 + tid;                                             \
            const int krow = cid >> 3, kcc = cid & 7;                                  \
            load_lds16(kb + (size_t)((kv0_) + krow) * 64 + ((kcc ^ (krow & 7)) << 3),  \
                       &lK[bufi][(j * 256 + wave * 64) * 8]);                          \
            const int vrow = cid >> 4, vcc = cid & 15;                                 \
            const int vsw = (vcc & 8) | ((vcc & 7) ^ (vrow & 7));                      \
            load_lds16(vb + (size_t)vrow * 2048 + (kv0_) + (vsw << 3),                 \
                       &lV[bufi][(j * 256 + wave * 64) * 8]);                          \
        }                                                                              \
    }

    ASTAGE(0, kv_lo);
    __syncthreads();

    for (int it = 0; it < niter; ++it) {
        const int cur = it & 1;
        if (it + 1 < niter) ASTAGE(cur ^ 1, kv_lo + (it + 1) * 128);

#pragma unroll
        for (int hh = 0; hh < 2; ++hh) {
            const int kv0 = kv_lo + it * 128 + hh * 64;
            if (kv0 < kv_hi && kv0 <= q0 + wave * 16 + 15) {   // wave-uniform guard
                // ---- S^T = K . Q^T
                f32x4 s[4];
#pragma unroll
                for (int n = 0; n < 4; ++n) {
                    const int row = hh * 64 + n * 16 + lr;
                    const bf16x8 kf0 =
                        *(const bf16x8*)&lK[cur][row * 64 + ((lg ^ (row & 7)) << 3)];
                    const bf16x8 kf1 =
                        *(const bf16x8*)&lK[cur][row * 64 + (((4 + lg) ^ (row & 7)) << 3)];
                    f32x4 a = (f32x4){0.f, 0.f, 0.f, 0.f};
                    a = MFMA(kf0, qf0, a);
                    a = MFMA(kf1, qf1, a);
                    s[n] = a;
                }

                // ---- p = exp2(s), causal zero, P store (kv-contiguous b64)
                const bool msk = (kv0 + 63 > q0 + wave * 16);
#pragma unroll
                for (int n = 0; n < 4; ++n) {
                    u16x4 pk;
#pragma unroll
                    for (int r = 0; r < 4; ++r) {
                        const int kvi = kv0 + n * 16 + lg * 4 + r;
                        const float p = (!msk || kvi <= myrow) ? exp2f(s[n][r]) : 0.f;
                        rs += p;
                        pk[r] = f2bf(p);
                    }
                    *(u16x4*)&lP[wave][lr * PPITCH + n * 16 + lg * 4] = pk;
                }

                // ---- PV
#pragma unroll
                for (int kc = 0; kc < 2; ++kc) {
                    const bf16x8 pf =
                        *(const bf16x8*)&lP[wave][lr * PPITCH + kc * 32 + lg * 8];
#pragma unroll
                    for (int n = 0; n < 4; ++n) {
                        const int row = n * 16 + lr;
                        const int c = hh * 8 + kc * 4 + lg;
                        const int csw = (c & 8) | ((c & 7) ^ (row & 7));
                        const bf16x8 vf = *(const bf16x8*)&lV[cur][row * 128 + (csw << 3)];
                        oacc[n] = MFMA(pf, vf, oacc[n]);
                    }
                }
            }
        }
        __syncthreads();
    }

    // ---- row-sum across the 4 lanes sharing lr
    rs += __shfl_xor(rs, 16);
    rs += __shfl_xor(rs, 32);
    if (lane < 16) Lp[slot * 64 + wave * 16 + lr] = rs;

    // ---- bf16 partials, MFMA-native layout:
    // idx = slot*4096 + wave*1024 + n*256 + (lg*4+r)*16 + lr
    u16* op = Opb + (size_t)slot * 4096 + wave * 1024;
#pragma unroll
    for (int n = 0; n < 4; ++n)
#pragma unroll
        for (int r = 0; r < 4; ++r)
            op[n * 256 + (lg * 4 + r) * 16 + lr] = f2bf(oacc[n][r]);
}

// ---------------------------------------------------------------------------
// Kernel 4: merge <=4 kv-chunk partials (plain sums; fixed max) + normalize.
// ---------------------------------------------------------------------------
__global__ __launch_bounds__(256) void attn_combine(const u16* __restrict__ Opb,
                                                    const float* __restrict__ Lp,
                                                    float* __restrict__ out) {
    const int gid = blockIdx.x * 256 + threadIdx.x;   // 1048576
    const int col = gid & 63;
    const int row = gid >> 6;            // b*2048 + t
    const int b = row >> 11, tt = row & 2047;
    const int qt = tt >> 6, i = tt & 63;
    const int nc = (qt >> 3) + 1;
    const size_t sbase = (size_t)(b * 32 + qt) * 4;
    const int sub = (i >> 4) * 1024 + (col >> 4) * 256 + (i & 15) * 16 + (col & 15);

    float O = 0.f, L = 0.f;
    for (int c = 0; c < nc; ++c) {
        O += bf2f(Opb[(sbase + c) * 4096 + sub]);
        L += Lp[(sbase + c) * 64 + i];
    }
    out[(size_t)row * 64 + col] = O / L;
}

// ---------------------------------------------------------------------------
extern "C" void kernel_launch(void* const* d_in, const int* in_sizes, int n_in,
                              void* d_out, int out_size, void* d_ws, size_t ws_size,
                              hipStream_t stream) {
    const float* x = (const float*)d_in[0];
    const float* Wq = (const float*)d_in[1];
    const float* Wk = (const float*)d_in[2];
    const float* Wv = (const float*)d_in[3];
    float* out = (float*)d_out;

    char* ws = (char*)d_ws;
    u16* Wtt = (u16*)ws;                                  // 384 KB @ 0
    u16* qb = (u16*)(ws + (512 << 10));                   // 2 MB
    u16* kb = (u16*)(ws + (512 << 10) + (2 << 20));       // 2 MB
    u16* vT = (u16*)(ws + (512 << 10) + (4 << 20));       // 2 MB
    u16* Opb = (u16*)(ws + (8 << 20));                    // 1024*4096*2 = 8.4 MB
    float* Lp = (float*)(ws + (20 << 20));                // 1024*64*4 = 256 KB

    wt_pack<<<1024, 192, 0, stream>>>(Wq, Wk, Wv, Wtt);
    qkv_gemm<<<256, 512, 0, stream>>>(x, Wtt, qb, kb, vT);
    attn_part<<<640, 256, 0, stream>>>(qb, kb, vT, Opb, Lp);
    attn_combine<<<4096, 256, 0, stream>>>(Opb, Lp, out);
}